// Round 9
// baseline (157.769 us; speedup 1.0000x reference)
//
#include <hip/hip_runtime.h>

#define B_ 2
#define T_ 2048
#define D_ 1024
#define H_ 16
#define HD_ 64
#define NT_ (B_*T_)   // 4096

typedef __attribute__((ext_vector_type(8))) short bf16x8;
typedef __attribute__((ext_vector_type(4))) float f32x4;
typedef __attribute__((ext_vector_type(4))) int i32x4;

static __device__ __forceinline__ unsigned short f2bf(float f) {
    union { float f; unsigned u; } v; v.f = f;
    unsigned r = v.u + 0x7fffu + ((v.u >> 16) & 1u);
    return (unsigned short)(r >> 16);
}

static __device__ __forceinline__ float exp2a(float x) {
    float r; asm("v_exp_f32 %0, %1" : "=v"(r) : "v"(x)); return r;
}

static __device__ __forceinline__ unsigned cvt_pk_bf16(float lo, float hi) {
    unsigned r; asm("v_cvt_pk_bf16_f32 %0, %1, %2" : "=v"(r) : "v"(lo), "v"(hi)); return r;
}

static __device__ __forceinline__ void gload_lds16(const unsigned short* g, unsigned short* l) {
    __builtin_amdgcn_global_load_lds(
        (const __attribute__((address_space(1))) unsigned int*)g,
        (__attribute__((address_space(3))) unsigned int*)l, 16, 0, 0);
}

// ---------------- cast f32 -> bf16 (8 el/thread) ----------------
__global__ __launch_bounds__(256) void cast_f32_bf16(
    const float* __restrict__ in, unsigned short* __restrict__ out, int n) {
    int base = (blockIdx.x * blockDim.x + threadIdx.x) * 8;
    if (base >= n) return;
    f32x4 a = *(const f32x4*)(in + base);
    f32x4 b = *(const f32x4*)(in + base + 4);
    unsigned short o[8];
#pragma unroll
    for (int j = 0; j < 4; ++j) { o[j] = f2bf(a[j]); o[j + 4] = f2bf(b[j]); }
    *(i32x4*)(out + base) = *(const i32x4*)o;
}

// ---------------- transpose + cast: W (RxC f32) -> WT (CxR bf16) ----------------
__global__ __launch_bounds__(256) void transpose_cast(
    const float* __restrict__ in, unsigned short* __restrict__ out, int R, int C) {
    __shared__ float tile[32][33];
    int c0 = blockIdx.x * 32, r0 = blockIdx.y * 32;
    int tx = threadIdx.x, ty = threadIdx.y;
#pragma unroll
    for (int j = 0; j < 32; j += 8)
        tile[ty + j][tx] = in[(size_t)(r0 + ty + j) * C + c0 + tx];
    __syncthreads();
#pragma unroll
    for (int j = 0; j < 32; j += 8)
        out[(size_t)(c0 + ty + j) * R + r0 + tx] = f2bf(tile[tx][ty + j]);
}

// ---------------- GEMM via global_load_lds, linear [128][32] LDS (m97 pattern) ----------
template <int EPI>
__global__ __launch_bounds__(256) void gemm_bt(
    const unsigned short* __restrict__ A, const unsigned short* __restrict__ Bt,
    float* __restrict__ C,
    unsigned short* __restrict__ Qo, unsigned short* __restrict__ Ko,
    unsigned short* __restrict__ Vo,
    int M, int N, int K) {
    __shared__ __align__(16) unsigned short As[128 * 32];
    __shared__ __align__(16) unsigned short Bs[128 * 32];
    int tid = threadIdx.x;
    int wv = tid >> 6, lane = tid & 63;
    int wr = wv >> 1, wc = wv & 1;
    int l15 = lane & 15, lg = lane >> 4;
    int tm = blockIdx.y * 128, tn = blockIdx.x * 128;
    f32x4 acc[4][4] = {};

    int lrow = lane >> 2, lcol = (lane & 3) * 8;

    for (int kt = 0; kt < K; kt += 32) {
        __syncthreads();
#pragma unroll
        for (int c = 0; c < 2; ++c) {
            int chunk = wv + c * 4;
            gload_lds16(A + (size_t)(tm + chunk * 16 + lrow) * K + kt + lcol, As + chunk * 512);
            gload_lds16(Bt + (size_t)(tn + chunk * 16 + lrow) * K + kt + lcol, Bs + chunk * 512);
        }
        __syncthreads();
        bf16x8 af[4], bfr[4];
#pragma unroll
        for (int m = 0; m < 4; ++m)
            af[m] = *(const bf16x8*)(As + (wr * 64 + m * 16 + l15) * 32 + lg * 8);
#pragma unroll
        for (int n = 0; n < 4; ++n)
            bfr[n] = *(const bf16x8*)(Bs + (wc * 64 + n * 16 + l15) * 32 + lg * 8);
#pragma unroll
        for (int m = 0; m < 4; ++m)
#pragma unroll
            for (int n = 0; n < 4; ++n)
                acc[m][n] = __builtin_amdgcn_mfma_f32_16x16x32_bf16(af[m], bfr[n], acc[m][n], 0, 0, 0);
    }

    if (EPI == 0) {
#pragma unroll
        for (int m = 0; m < 4; ++m) {
            int row0 = tm + wr * 64 + m * 16 + lg * 4;
#pragma unroll
            for (int n = 0; n < 4; ++n) {
                int col = tn + wc * 64 + n * 16 + l15;
#pragma unroll
                for (int r = 0; r < 4; ++r)
                    C[(size_t)(row0 + r) * N + col] = acc[m][n][r];
            }
        }
    } else {
        const float SC = 0.125f * 1.44269504f;
#pragma unroll
        for (int m = 0; m < 4; ++m) {
            int row0 = tm + wr * 64 + m * 16 + lg * 4;
#pragma unroll
            for (int n = 0; n < 4; ++n) {
                int e = tn + wc * 64 + n * 16 + l15;
                int sec = e >> 10, rem = e & 1023;
                int h = rem >> 6, hd = rem & 63;
                int tok = row0;
                int b = tok >> 11, tl = tok & 2047;
                if (sec == 2) {
                    size_t idx0 = ((size_t)(b * H_ + h) * HD_ + hd) * T_ + tl;
                    *(unsigned*)(Vo + idx0)     = cvt_pk_bf16(acc[m][n][0], acc[m][n][1]);
                    *(unsigned*)(Vo + idx0 + 2) = cvt_pk_bf16(acc[m][n][2], acc[m][n][3]);
                } else {
                    unsigned short* dst = (sec == 0) ? Qo : Ko;
                    float sc = (sec == 0) ? SC : 1.0f;
#pragma unroll
                    for (int r = 0; r < 4; ++r)
                        dst[(((size_t)(b * H_ + h) * T_ + tl + r) << 6) + hd] =
                            f2bf(acc[m][n][r] * sc);
                }
            }
        }
    }
}

// ---------------- flash attention v9: single-barrier double-buffered pipeline ----------
// Per tile t: QK(t) -> LDS-write(t+1 -> other buf) -> issue loads(t+2) -> softmax+PV(t)
// -> ONE barrier. Buffer rewritten 2 barriers after last read. Math identical to v5/v8.
#define KPAD 72
#define VPAD 136

#define FL_ITER(C, NC, WS, LS, DOW, DOL, KT)                                        \
  do {                                                                              \
    f32x4 s2[2][4];                                                                 \
    __builtin_amdgcn_s_setprio(1);                                                  \
    _Pragma("unroll")                                                               \
    for (int h2 = 0; h2 < 2; ++h2)                                                  \
      _Pragma("unroll")                                                             \
      for (int kf = 0; kf < 4; ++kf) {                                              \
        const unsigned short* kr = Ks##C + (h2 * 64 + kf * 16 + l15) * KPAD;        \
        bf16x8 ka = *(const bf16x8*)(kr + lg * 8);                                  \
        bf16x8 kb = *(const bf16x8*)(kr + 32 + lg * 8);                             \
        f32x4 z = {};                                                               \
        z = __builtin_amdgcn_mfma_f32_16x16x32_bf16(ka, qf0, z, 0, 0, 0);           \
        z = __builtin_amdgcn_mfma_f32_16x16x32_bf16(kb, qf1, z, 0, 0, 0);           \
        s2[h2][kf] = z;                                                             \
      }                                                                             \
    __builtin_amdgcn_s_setprio(0);                                                  \
    if (DOW) {                                                                      \
      _Pragma("unroll")                                                             \
      for (int c = 0; c < 2; ++c) {                                                 \
        int idx = tid + c * 512;                                                    \
        *(i32x4*)(Ks##NC + (idx >> 3) * KPAD + (idx & 7) * 8) = kv##WS[c];          \
        *(i32x4*)(VTs##NC + (idx >> 4) * VPAD + (idx & 15) * 8) = vv##WS[c];        \
      }                                                                             \
      int mA_ = mask[b * T_ + (KT) + 128 + lane];                                   \
      int mB_ = mask[b * T_ + (KT) + 192 + lane];                                   \
      nmb##NC = __all(mA_ != 0 && mB_ != 0);                                        \
      if (!nmb##NC && wv == 0) {                                                    \
        bias##NC[lane] = mA_ ? 0.f : -1e30f;                                        \
        bias##NC[64 + lane] = mB_ ? 0.f : -1e30f;                                   \
      }                                                                             \
    }                                                                               \
    if (DOL) {                                                                      \
      _Pragma("unroll")                                                             \
      for (int c = 0; c < 2; ++c) {                                                 \
        int idx = tid + c * 512;                                                    \
        kv##LS[c] = *(const i32x4*)(Kb + (size_t)((KT) + 256 + (idx >> 3)) * HD_ +  \
                                    (idx & 7) * 8);                                 \
        vv##LS[c] = *(const i32x4*)(VTb + (size_t)(idx >> 4) * T_ + (KT) + 256 +    \
                                    (idx & 15) * 8);                                \
      }                                                                             \
    }                                                                               \
    if (!nmb##C) {                                                                  \
      _Pragma("unroll")                                                             \
      for (int h2 = 0; h2 < 2; ++h2)                                                \
        _Pragma("unroll")                                                           \
        for (int kf = 0; kf < 4; ++kf)                                              \
          _Pragma("unroll")                                                         \
          for (int r = 0; r < 4; ++r)                                               \
            s2[h2][kf][r] += bias##C[h2 * 64 + kf * 16 + lg * 4 + r];               \
    }                                                                               \
    _Pragma("unroll")                                                               \
    for (int h2 = 0; h2 < 2; ++h2) {                                                \
      float p[4][4];                                                                \
      _Pragma("unroll")                                                             \
      for (int kf = 0; kf < 4; ++kf)                                                \
        _Pragma("unroll")                                                           \
        for (int r = 0; r < 4; ++r) {                                               \
          float pv = exp2a(s2[h2][kf][r] - M0);                                     \
          p[kf][r] = pv;                                                            \
          l_part += pv;                                                             \
        }                                                                           \
      unsigned pk0_0 = cvt_pk_bf16(p[0][0], p[0][1]);                               \
      unsigned pk0_1 = cvt_pk_bf16(p[0][2], p[0][3]);                               \
      unsigned pk1_0 = cvt_pk_bf16(p[1][0], p[1][1]);                               \
      unsigned pk1_1 = cvt_pk_bf16(p[1][2], p[1][3]);                               \
      unsigned pk2_0 = cvt_pk_bf16(p[2][0], p[2][1]);                               \
      unsigned pk2_1 = cvt_pk_bf16(p[2][2], p[2][3]);                               \
      unsigned pk3_0 = cvt_pk_bf16(p[3][0], p[3][1]);                               \
      unsigned pk3_1 = cvt_pk_bf16(p[3][2], p[3][3]);                               \
      union { bf16x8 v; unsigned u[4]; } P0, P1;                                    \
      {                                                                             \
        unsigned a0 = __shfl((int)pk0_0, srcA), b0 = __shfl((int)pk1_0, srcA);      \
        unsigned a1 = __shfl((int)pk0_1, srcA), b1 = __shfl((int)pk1_1, srcA);      \
        unsigned a2 = __shfl((int)pk0_0, srcB), b2 = __shfl((int)pk1_0, srcB);      \
        unsigned a3 = __shfl((int)pk0_1, srcB), b3 = __shfl((int)pk1_1, srcB);      \
        P0.u[0] = hi ? b0 : a0;                                                     \
        P0.u[1] = hi ? b1 : a1;                                                     \
        P0.u[2] = hi ? b2 : a2;                                                     \
        P0.u[3] = hi ? b3 : a3;                                                     \
      }                                                                             \
      {                                                                             \
        unsigned a0 = __shfl((int)pk2_0, srcA), b0 = __shfl((int)pk3_0, srcA);      \
        unsigned a1 = __shfl((int)pk2_1, srcA), b1 = __shfl((int)pk3_1, srcA);      \
        unsigned a2 = __shfl((int)pk2_0, srcB), b2 = __shfl((int)pk3_0, srcB);      \
        unsigned a3 = __shfl((int)pk2_1, srcB), b3 = __shfl((int)pk3_1, srcB);      \
        P1.u[0] = hi ? b0 : a0;                                                     \
        P1.u[1] = hi ? b1 : a1;                                                     \
        P1.u[2] = hi ? b2 : a2;                                                     \
        P1.u[3] = hi ? b3 : a3;                                                     \
      }                                                                             \
      __builtin_amdgcn_s_setprio(1);                                                \
      _Pragma("unroll")                                                             \
      for (int df = 0; df < 4; ++df) {                                              \
        const unsigned short* vr = VTs##C + (df * 16 + l15) * VPAD + h2 * 64;       \
        bf16x8 va = *(const bf16x8*)(vr + lg * 8);                                  \
        bf16x8 vb = *(const bf16x8*)(vr + 32 + lg * 8);                             \
        o_acc[df] = __builtin_amdgcn_mfma_f32_16x16x32_bf16(P0.v, va, o_acc[df], 0, 0, 0); \
        o_acc[df] = __builtin_amdgcn_mfma_f32_16x16x32_bf16(P1.v, vb, o_acc[df], 0, 0, 0); \
      }                                                                             \
      __builtin_amdgcn_s_setprio(0);                                                \
    }                                                                               \
    __syncthreads();                                                                \
  } while (0)

__global__ __launch_bounds__(512) void flash_attn(
    const unsigned short* __restrict__ Qg, const unsigned short* __restrict__ Kg,
    const unsigned short* __restrict__ VTg, const int* __restrict__ mask,
    unsigned short* __restrict__ AO) {
    __shared__ __align__(16) unsigned short Ks0[128 * KPAD];
    __shared__ __align__(16) unsigned short Ks1[128 * KPAD];
    __shared__ __align__(16) unsigned short VTs0[64 * VPAD];
    __shared__ __align__(16) unsigned short VTs1[64 * VPAD];
    __shared__ float bias0[128];
    __shared__ float bias1[128];

    int tid = threadIdx.x, wv = tid >> 6, lane = tid & 63;
    int l15 = lane & 15, lg = lane >> 4;
    int bh = blockIdx.y;
    int b = bh >> 4, h = bh & 15;
    int q0 = blockIdx.x * 128;
    const unsigned short* Qb  = Qg  + (size_t)bh * T_ * HD_;
    const unsigned short* Kb  = Kg  + (size_t)bh * T_ * HD_;
    const unsigned short* VTb = VTg + (size_t)bh * HD_ * T_;

    // issue tile-0/1 K,V loads first (max latency hiding under Q staging + barriers)
    i32x4 kvA[2], vvA[2], kvB[2], vvB[2];
#pragma unroll
    for (int c = 0; c < 2; ++c) {
        int idx = tid + c * 512;
        kvA[c] = *(const i32x4*)(Kb + (size_t)(idx >> 3) * HD_ + (idx & 7) * 8);
        vvA[c] = *(const i32x4*)(VTb + (size_t)(idx >> 4) * T_ + (idx & 15) * 8);
        kvB[c] = *(const i32x4*)(Kb + (size_t)(128 + (idx >> 3)) * HD_ + (idx & 7) * 8);
        vvB[c] = *(const i32x4*)(VTb + (size_t)(idx >> 4) * T_ + 128 + (idx & 15) * 8);
    }

    {   // stage Q tile (128x64) into Ks0
        int sr = tid >> 2, sc = (tid & 3) * 16;
        i32x4 v0 = *(const i32x4*)(Qb + (size_t)(q0 + sr) * HD_ + sc);
        i32x4 v1 = *(const i32x4*)(Qb + (size_t)(q0 + sr) * HD_ + sc + 8);
        *(i32x4*)(Ks0 + sr * KPAD + sc) = v0;
        *(i32x4*)(Ks0 + sr * KPAD + sc + 8) = v1;
    }
    __syncthreads();
    bf16x8 qf0 = *(const bf16x8*)(Ks0 + (wv * 16 + l15) * KPAD + lg * 8);
    bf16x8 qf1 = *(const bf16x8*)(Ks0 + (wv * 16 + l15) * KPAD + 32 + lg * 8);
    __syncthreads();   // all qf reads done before Ks0 is overwritten

    bool nmb0, nmb1;
    {   // prologue: write tile 0 into buf0 + bias0
#pragma unroll
        for (int c = 0; c < 2; ++c) {
            int idx = tid + c * 512;
            *(i32x4*)(Ks0 + (idx >> 3) * KPAD + (idx & 7) * 8) = kvA[c];
            *(i32x4*)(VTs0 + (idx >> 4) * VPAD + (idx & 15) * 8) = vvA[c];
        }
        int mA_ = mask[b * T_ + lane];
        int mB_ = mask[b * T_ + 64 + lane];
        nmb0 = __all(mA_ != 0 && mB_ != 0);
        if (!nmb0 && wv == 0) {
            bias0[lane] = mA_ ? 0.f : -1e30f;
            bias0[64 + lane] = mB_ ? 0.f : -1e30f;
        }
    }
    __syncthreads();

    const float M0 = 8.0f;
    float l_part = 0.f;
    f32x4 o_acc[4] = {};
    int srcA = l15 + 16 * ((lg & 1) * 2);
    int srcB = srcA + 16;
    bool hi = (lg & 2) != 0;

    int kt = 0;
    for (int tp = 0; tp < 7; ++tp) {
        FL_ITER(0, 1, B, A, true, true, kt); kt += 128;   // t even
        FL_ITER(1, 0, A, B, true, true, kt); kt += 128;   // t odd
    }
    FL_ITER(0, 1, B, A, true, false, kt); kt += 128;      // t = 14
    FL_ITER(1, 0, A, B, false, false, kt);                // t = 15

    // final deferred l reduction; broadcast to O layout; write AO bf16
    l_part += __shfl_xor(l_part, 16);
    l_part += __shfl_xor(l_part, 32);
    float l_o[4];
#pragma unroll
    for (int r = 0; r < 4; ++r) l_o[r] = __shfl(l_part, lg * 4 + r);
#pragma unroll
    for (int df = 0; df < 4; ++df)
#pragma unroll
        for (int r = 0; r < 4; ++r) {
            int t = q0 + wv * 16 + lg * 4 + r;
            AO[(size_t)(b * T_ + t) * D_ + h * 64 + df * 16 + l15] =
                f2bf(o_acc[df][r] / l_o[r]);
        }
}

extern "C" void kernel_launch(void* const* d_in, const int* in_sizes, int n_in,
                              void* d_out, int out_size, void* d_ws, size_t ws_size,
                              hipStream_t stream) {
    const float* x    = (const float*)d_in[0];
    const int*   mask = (const int*)d_in[1];
    const float* Wqkv = (const float*)d_in[2];
    const float* Wout = (const float*)d_in[3];
    float* out = (float*)d_out;
    char* ws = (char*)d_ws;

    unsigned short* Xb    = (unsigned short*)(ws);                       // 8 MB
    unsigned short* WqkvT = (unsigned short*)(ws + (size_t)(8u << 20));  // 6 MB
    unsigned short* WoutT = (unsigned short*)(ws + (size_t)(14u << 20)); // 2 MB
    unsigned short* Qg    = (unsigned short*)(ws + (size_t)(16u << 20)); // 8 MB
    unsigned short* Kg    = (unsigned short*)(ws + (size_t)(24u << 20)); // 8 MB
    unsigned short* VT    = (unsigned short*)(ws + (size_t)(32u << 20)); // 8 MB (V transposed)
    unsigned short* AO    = Xb;  // overlay: Xb dead after QKV GEMM

    cast_f32_bf16<<<2048, 256, 0, stream>>>(x, Xb, NT_ * D_);
    transpose_cast<<<dim3(3072 / 32, 1024 / 32), dim3(32, 8), 0, stream>>>(Wqkv, WqkvT, 1024, 3072);
    transpose_cast<<<dim3(1024 / 32, 1024 / 32), dim3(32, 8), 0, stream>>>(Wout, WoutT, 1024, 1024);
    gemm_bt<1><<<dim3(3072 / 128, 4096 / 128), 256, 0, stream>>>(
        Xb, WqkvT, nullptr, Qg, Kg, VT, NT_, 3 * D_, D_);
    flash_attn<<<dim3(T_ / 128, B_ * H_), 512, 0, stream>>>(Qg, Kg, VT, mask, AO);
    gemm_bt<0><<<dim3(1024 / 128, 4096 / 128), 256, 0, stream>>>(
        AO, WoutT, out, nullptr, nullptr, nullptr, NT_, D_, D_);
}

// Round 10
// 138.269 us; speedup vs baseline: 1.1410x; 1.1410x over previous
//
#include <hip/hip_runtime.h>

#define B_ 2
#define T_ 2048
#define D_ 1024
#define H_ 16
#define HD_ 64
#define NT_ (B_*T_)   // 4096

typedef __attribute__((ext_vector_type(8))) short bf16x8;
typedef __attribute__((ext_vector_type(4))) float f32x4;
typedef __attribute__((ext_vector_type(16))) float f32x16;
typedef __attribute__((ext_vector_type(4))) int i32x4;

#define MFMA32(a, b, c) __builtin_amdgcn_mfma_f32_32x32x16_bf16((a), (b), (c), 0, 0, 0)

static __device__ __forceinline__ unsigned short f2bf(float f) {
    union { float f; unsigned u; } v; v.f = f;
    unsigned r = v.u + 0x7fffu + ((v.u >> 16) & 1u);
    return (unsigned short)(r >> 16);
}

static __device__ __forceinline__ float exp2a(float x) {
    float r; asm("v_exp_f32 %0, %1" : "=v"(r) : "v"(x)); return r;
}

static __device__ __forceinline__ unsigned cvt_pk_bf16(float lo, float hi) {
    unsigned r; asm("v_cvt_pk_bf16_f32 %0, %1, %2" : "=v"(r) : "v"(lo), "v"(hi)); return r;
}

static __device__ __forceinline__ void gload_lds16(const unsigned short* g, unsigned short* l) {
    __builtin_amdgcn_global_load_lds(
        (const __attribute__((address_space(1))) unsigned int*)g,
        (__attribute__((address_space(3))) unsigned int*)l, 16, 0, 0);
}

// ---------------- cast f32 -> bf16 (8 el/thread) ----------------
__global__ __launch_bounds__(256) void cast_f32_bf16(
    const float* __restrict__ in, unsigned short* __restrict__ out, int n) {
    int base = (blockIdx.x * blockDim.x + threadIdx.x) * 8;
    if (base >= n) return;
    f32x4 a = *(const f32x4*)(in + base);
    f32x4 b = *(const f32x4*)(in + base + 4);
    unsigned short o[8];
#pragma unroll
    for (int j = 0; j < 4; ++j) { o[j] = f2bf(a[j]); o[j + 4] = f2bf(b[j]); }
    *(i32x4*)(out + base) = *(const i32x4*)o;
}

// ---------------- transpose + cast: W (RxC f32) -> WT (CxR bf16) ----------------
__global__ __launch_bounds__(256) void transpose_cast(
    const float* __restrict__ in, unsigned short* __restrict__ out, int R, int C) {
    __shared__ float tile[32][33];
    int c0 = blockIdx.x * 32, r0 = blockIdx.y * 32;
    int tx = threadIdx.x, ty = threadIdx.y;
#pragma unroll
    for (int j = 0; j < 32; j += 8)
        tile[ty + j][tx] = in[(size_t)(r0 + ty + j) * C + c0 + tx];
    __syncthreads();
#pragma unroll
    for (int j = 0; j < 32; j += 8)
        out[(size_t)(c0 + ty + j) * R + r0 + tx] = f2bf(tile[tx][ty + j]);
}

// ---------------- GEMM via global_load_lds, linear [128][32] LDS (m97 pattern) ----------
template <int EPI>
__global__ __launch_bounds__(256) void gemm_bt(
    const unsigned short* __restrict__ A, const unsigned short* __restrict__ Bt,
    float* __restrict__ C,
    unsigned short* __restrict__ Qo, unsigned short* __restrict__ Ko,
    unsigned short* __restrict__ Vo,
    int M, int N, int K) {
    __shared__ __align__(16) unsigned short As[128 * 32];
    __shared__ __align__(16) unsigned short Bs[128 * 32];
    int tid = threadIdx.x;
    int wv = tid >> 6, lane = tid & 63;
    int wr = wv >> 1, wc = wv & 1;
    int l15 = lane & 15, lg = lane >> 4;
    int tm = blockIdx.y * 128, tn = blockIdx.x * 128;
    f32x4 acc[4][4] = {};

    int lrow = lane >> 2, lcol = (lane & 3) * 8;

    for (int kt = 0; kt < K; kt += 32) {
        __syncthreads();
#pragma unroll
        for (int c = 0; c < 2; ++c) {
            int chunk = wv + c * 4;
            gload_lds16(A + (size_t)(tm + chunk * 16 + lrow) * K + kt + lcol, As + chunk * 512);
            gload_lds16(Bt + (size_t)(tn + chunk * 16 + lrow) * K + kt + lcol, Bs + chunk * 512);
        }
        __syncthreads();
        bf16x8 af[4], bfr[4];
#pragma unroll
        for (int m = 0; m < 4; ++m)
            af[m] = *(const bf16x8*)(As + (wr * 64 + m * 16 + l15) * 32 + lg * 8);
#pragma unroll
        for (int n = 0; n < 4; ++n)
            bfr[n] = *(const bf16x8*)(Bs + (wc * 64 + n * 16 + l15) * 32 + lg * 8);
#pragma unroll
        for (int m = 0; m < 4; ++m)
#pragma unroll
            for (int n = 0; n < 4; ++n)
                acc[m][n] = __builtin_amdgcn_mfma_f32_16x16x32_bf16(af[m], bfr[n], acc[m][n], 0, 0, 0);
    }

    if (EPI == 0) {
#pragma unroll
        for (int m = 0; m < 4; ++m) {
            int row0 = tm + wr * 64 + m * 16 + lg * 4;
#pragma unroll
            for (int n = 0; n < 4; ++n) {
                int col = tn + wc * 64 + n * 16 + l15;
#pragma unroll
                for (int r = 0; r < 4; ++r)
                    C[(size_t)(row0 + r) * N + col] = acc[m][n][r];
            }
        }
    } else {
        const float SC = 0.125f * 1.44269504f;   // folded into Q
#pragma unroll
        for (int m = 0; m < 4; ++m) {
            int row0 = tm + wr * 64 + m * 16 + lg * 4;
#pragma unroll
            for (int n = 0; n < 4; ++n) {
                int e = tn + wc * 64 + n * 16 + l15;
                int sec = e >> 10, rem = e & 1023;
                int h = rem >> 6, hd = rem & 63;
                int tok = row0;
                int b = tok >> 11, tl = tok & 2047;
                if (sec == 2) {
                    size_t idx0 = ((size_t)(b * H_ + h) * HD_ + hd) * T_ + tl;
                    *(unsigned*)(Vo + idx0)     = cvt_pk_bf16(acc[m][n][0], acc[m][n][1]);
                    *(unsigned*)(Vo + idx0 + 2) = cvt_pk_bf16(acc[m][n][2], acc[m][n][3]);
                } else {
                    unsigned short* dst = (sec == 0) ? Qo : Ko;
                    float sc = (sec == 0) ? SC : 1.0f;
#pragma unroll
                    for (int r = 0; r < 4; ++r)
                        dst[(((size_t)(b * H_ + h) * T_ + tl + r) << 6) + hd] =
                            f2bf(acc[m][n][r] * sc);
                }
            }
        }
    }
}

// ---------------- flash attention v10: 32x32 MFMA, shfl_xor(32)-only P exchange ----------
// S^T[k][q] = mfma32(K,Q): lane holds col q=l31, rows k=(reg&3)+8*(reg>>2)+4*hi.
// PV A-frag P[q][k=kc*16+8*hi+jj]: jj0-3 from hi=0 owners, jj4-7 from hi=1 owners,
// reg-blocks {8*hf, 8*hf+4} -> own/partner via ONE shfl_xor(,32) pair per chunk.
#define KPAD 72
#define VPAD 136

#define EXCH(PV, HF, FRAG)                                                     \
  do {                                                                         \
    unsigned uA0 = cvt_pk_bf16(PV[8 * HF + 0], PV[8 * HF + 1]);                \
    unsigned uA1 = cvt_pk_bf16(PV[8 * HF + 2], PV[8 * HF + 3]);                \
    unsigned uB0 = cvt_pk_bf16(PV[8 * HF + 4], PV[8 * HF + 5]);                \
    unsigned uB1 = cvt_pk_bf16(PV[8 * HF + 6], PV[8 * HF + 7]);                \
    unsigned snd0 = hi ? uA0 : uB0, snd1 = hi ? uA1 : uB1;                     \
    unsigned rc0 = (unsigned)__shfl_xor((int)snd0, 32);                        \
    unsigned rc1 = (unsigned)__shfl_xor((int)snd1, 32);                        \
    union { bf16x8 v; unsigned u[4]; } Fx;                                     \
    Fx.u[0] = hi ? rc0 : uA0;                                                  \
    Fx.u[1] = hi ? rc1 : uA1;                                                  \
    Fx.u[2] = hi ? uB0 : rc0;                                                  \
    Fx.u[3] = hi ? uB1 : rc1;                                                  \
    FRAG = Fx.v;                                                               \
  } while (0)

__global__ __launch_bounds__(256) void flash_attn(
    const unsigned short* __restrict__ Qg, const unsigned short* __restrict__ Kg,
    const unsigned short* __restrict__ VTg, const int* __restrict__ mask,
    unsigned short* __restrict__ AO) {
    __shared__ __align__(16) unsigned short Ks[128 * KPAD];
    __shared__ __align__(16) unsigned short VTs[64 * VPAD];
    __shared__ float biasS[128];

    int tid = threadIdx.x, wv = tid >> 6, lane = tid & 63;
    int l31 = lane & 31, hi = lane >> 5;
    int bh = blockIdx.y;
    int b = bh >> 4, h = bh & 15;
    int q0 = blockIdx.x * 128;
    const unsigned short* Qb  = Qg  + (size_t)bh * T_ * HD_;
    const unsigned short* Kb  = Kg  + (size_t)bh * T_ * HD_;
    const unsigned short* VTb = VTg + (size_t)bh * HD_ * T_;

    // Q fragments direct from global: B-frag col=q(l31), kdim=8*hi+jj, hd = c*16+8*hi+jj
    bf16x8 qf[4];
    {
        const unsigned short* qrow = Qb + (size_t)(q0 + wv * 32 + l31) * HD_;
#pragma unroll
        for (int c = 0; c < 4; ++c)
            qf[c] = *(const bf16x8*)(qrow + c * 16 + hi * 8);
    }

    const float M0 = 8.0f;
    float l_part = 0.f;
    f32x16 o0 = {}, o1 = {};   // O[q-row][d = {0,1}*32 + l31]

    for (int kt = 0; kt < T_; kt += 128) {
        // reg prefetch (latency hides under barrier wait)
        i32x4 kv[4], vvv[4];
#pragma unroll
        for (int c = 0; c < 4; ++c) {
            int idx = tid + c * 256;
            kv[c]  = *(const i32x4*)(Kb + (size_t)(kt + (idx >> 3)) * HD_ + (idx & 7) * 8);
            vvv[c] = *(const i32x4*)(VTb + (size_t)(idx >> 4) * T_ + kt + (idx & 15) * 8);
        }
        int mA = mask[b * T_ + kt + lane];
        int mB = mask[b * T_ + kt + 64 + lane];
        bool nomask = __all(mA != 0 && mB != 0);

        __syncthreads();   // prev tile LDS reads done
#pragma unroll
        for (int c = 0; c < 4; ++c) {
            int idx = tid + c * 256;
            *(i32x4*)(Ks + (idx >> 3) * KPAD + (idx & 7) * 8) = kv[c];
            *(i32x4*)(VTs + (idx >> 4) * VPAD + (idx & 15) * 8) = vvv[c];
        }
        if (!nomask && wv == 0) {
            biasS[lane]      = mA ? 0.f : -1e30f;
            biasS[64 + lane] = mB ? 0.f : -1e30f;
        }
        __syncthreads();

        // two 64-key half-passes (keeps S register footprint at 32 f32)
#pragma unroll
        for (int hp = 0; hp < 2; ++hp) {
            f32x16 s0 = {}, s1 = {};
            __builtin_amdgcn_s_setprio(1);
#pragma unroll
            for (int c = 0; c < 4; ++c) {
                bf16x8 ka = *(const bf16x8*)(Ks + ((hp * 2 + 0) * 32 + l31) * KPAD + c * 16 + hi * 8);
                s0 = MFMA32(ka, qf[c], s0);
            }
#pragma unroll
            for (int c = 0; c < 4; ++c) {
                bf16x8 kb2 = *(const bf16x8*)(Ks + ((hp * 2 + 1) * 32 + l31) * KPAD + c * 16 + hi * 8);
                s1 = MFMA32(kb2, qf[c], s1);
            }
            __builtin_amdgcn_s_setprio(0);

            if (!nomask) {
#pragma unroll
                for (int i = 0; i < 16; ++i) {
                    int krow = (i & 3) + 8 * (i >> 2) + 4 * hi;
                    s0[i] += biasS[hp * 64 + krow];
                    s1[i] += biasS[hp * 64 + 32 + krow];
                }
            }
            // P = exp2(S - M0) in place; accumulate partial l
#pragma unroll
            for (int i = 0; i < 16; ++i) {
                s0[i] = exp2a(s0[i] - M0);
                s1[i] = exp2a(s1[i] - M0);
                l_part += s0[i] + s1[i];
            }
            // build 4 PV A-frags (k chunks of 16): kb=kc>>1 selects s0/s1, hf=kc&1
            bf16x8 fr0, fr1, fr2, fr3;
            EXCH(s0, 0, fr0);
            EXCH(s0, 1, fr1);
            EXCH(s1, 0, fr2);
            EXCH(s1, 1, fr3);

            __builtin_amdgcn_s_setprio(1);
#pragma unroll
            for (int kc = 0; kc < 4; ++kc) {
                bf16x8 fr = (kc == 0) ? fr0 : (kc == 1) ? fr1 : (kc == 2) ? fr2 : fr3;
                bf16x8 va = *(const bf16x8*)(VTs + l31 * VPAD + hp * 64 + kc * 16 + hi * 8);
                bf16x8 vb = *(const bf16x8*)(VTs + (32 + l31) * VPAD + hp * 64 + kc * 16 + hi * 8);
                o0 = MFMA32(fr, va, o0);
                o1 = MFMA32(fr, vb, o1);
            }
            __builtin_amdgcn_s_setprio(0);
        }
    }

    // merge l halves (hi=0 owns half the k's, hi=1 the other) -> full l per q=l31
    l_part += __shfl_xor(l_part, 32);

    // write AO[b][t=q0+wv*32+q_row][h*64 + dblk*32 + l31]
    size_t rowD = (size_t)(b * T_ + q0 + wv * 32) * D_ + h * 64;
#pragma unroll
    for (int i = 0; i < 16; ++i) {
        int qrow = (i & 3) + 8 * (i >> 2) + 4 * hi;
        float lq = __shfl(l_part, qrow);
        float inv = 1.0f / lq;
        AO[rowD + (size_t)qrow * D_ + l31]      = f2bf(o0[i] * inv);
        AO[rowD + (size_t)qrow * D_ + 32 + l31] = f2bf(o1[i] * inv);
    }
}

extern "C" void kernel_launch(void* const* d_in, const int* in_sizes, int n_in,
                              void* d_out, int out_size, void* d_ws, size_t ws_size,
                              hipStream_t stream) {
    const float* x    = (const float*)d_in[0];
    const int*   mask = (const int*)d_in[1];
    const float* Wqkv = (const float*)d_in[2];
    const float* Wout = (const float*)d_in[3];
    float* out = (float*)d_out;
    char* ws = (char*)d_ws;

    unsigned short* Xb    = (unsigned short*)(ws);                       // 8 MB
    unsigned short* WqkvT = (unsigned short*)(ws + (size_t)(8u << 20));  // 6 MB
    unsigned short* WoutT = (unsigned short*)(ws + (size_t)(14u << 20)); // 2 MB
    unsigned short* Qg    = (unsigned short*)(ws + (size_t)(16u << 20)); // 8 MB
    unsigned short* Kg    = (unsigned short*)(ws + (size_t)(24u << 20)); // 8 MB
    unsigned short* VT    = (unsigned short*)(ws + (size_t)(32u << 20)); // 8 MB (V transposed)
    unsigned short* AO    = Xb;  // overlay: Xb dead after QKV GEMM

    cast_f32_bf16<<<2048, 256, 0, stream>>>(x, Xb, NT_ * D_);
    transpose_cast<<<dim3(3072 / 32, 1024 / 32), dim3(32, 8), 0, stream>>>(Wqkv, WqkvT, 1024, 3072);
    transpose_cast<<<dim3(1024 / 32, 1024 / 32), dim3(32, 8), 0, stream>>>(Wout, WoutT, 1024, 1024);
    gemm_bt<1><<<dim3(3072 / 128, 4096 / 128), 256, 0, stream>>>(
        Xb, WqkvT, nullptr, Qg, Kg, VT, NT_, 3 * D_, D_);
    flash_attn<<<dim3(T_ / 128, B_ * H_), 256, 0, stream>>>(Qg, Kg, VT, mask, AO);
    gemm_bt<0><<<dim3(1024 / 128, 4096 / 128), 256, 0, stream>>>(
        AO, WoutT, out, nullptr, nullptr, nullptr, NT_, D_, D_);
}

// Round 11
// 136.966 us; speedup vs baseline: 1.1519x; 1.0095x over previous
//
#include <hip/hip_runtime.h>

#define B_ 2
#define T_ 2048
#define D_ 1024
#define H_ 16
#define HD_ 64
#define NT_ (B_*T_)   // 4096

typedef __attribute__((ext_vector_type(8))) short bf16x8;
typedef __attribute__((ext_vector_type(4))) float f32x4;
typedef __attribute__((ext_vector_type(16))) float f32x16;
typedef __attribute__((ext_vector_type(4))) int i32x4;

#define MFMA32(a, b, c) __builtin_amdgcn_mfma_f32_32x32x16_bf16((a), (b), (c), 0, 0, 0)

static __device__ __forceinline__ unsigned short f2bf(float f) {
    union { float f; unsigned u; } v; v.f = f;
    unsigned r = v.u + 0x7fffu + ((v.u >> 16) & 1u);
    return (unsigned short)(r >> 16);
}

static __device__ __forceinline__ float exp2a(float x) {
    float r; asm("v_exp_f32 %0, %1" : "=v"(r) : "v"(x)); return r;
}

static __device__ __forceinline__ unsigned cvt_pk_bf16(float lo, float hi) {
    unsigned r; asm("v_cvt_pk_bf16_f32 %0, %1, %2" : "=v"(r) : "v"(lo), "v"(hi)); return r;
}

static __device__ __forceinline__ void gload_lds16(const unsigned short* g, unsigned short* l) {
    __builtin_amdgcn_global_load_lds(
        (const __attribute__((address_space(1))) unsigned int*)g,
        (__attribute__((address_space(3))) unsigned int*)l, 16, 0, 0);
}

// ---------------- cast f32 -> bf16 (8 el/thread) ----------------
__global__ __launch_bounds__(256) void cast_f32_bf16(
    const float* __restrict__ in, unsigned short* __restrict__ out, int n) {
    int base = (blockIdx.x * blockDim.x + threadIdx.x) * 8;
    if (base >= n) return;
    f32x4 a = *(const f32x4*)(in + base);
    f32x4 b = *(const f32x4*)(in + base + 4);
    unsigned short o[8];
#pragma unroll
    for (int j = 0; j < 4; ++j) { o[j] = f2bf(a[j]); o[j + 4] = f2bf(b[j]); }
    *(i32x4*)(out + base) = *(const i32x4*)o;
}

// ---------------- transpose + cast: W (RxC f32) -> WT (CxR bf16) ----------------
__global__ __launch_bounds__(256) void transpose_cast(
    const float* __restrict__ in, unsigned short* __restrict__ out, int R, int C) {
    __shared__ float tile[32][33];
    int c0 = blockIdx.x * 32, r0 = blockIdx.y * 32;
    int tx = threadIdx.x, ty = threadIdx.y;
#pragma unroll
    for (int j = 0; j < 32; j += 8)
        tile[ty + j][tx] = in[(size_t)(r0 + ty + j) * C + c0 + tx];
    __syncthreads();
#pragma unroll
    for (int j = 0; j < 32; j += 8)
        out[(size_t)(c0 + ty + j) * R + r0 + tx] = f2bf(tile[tx][ty + j]);
}

// ---------------- GEMM via global_load_lds, linear [128][32] LDS (m97 pattern) ----------
template <int EPI>
__global__ __launch_bounds__(256) void gemm_bt(
    const unsigned short* __restrict__ A, const unsigned short* __restrict__ Bt,
    float* __restrict__ C,
    unsigned short* __restrict__ Qo, unsigned short* __restrict__ Ko,
    unsigned short* __restrict__ Vo,
    int M, int N, int K) {
    __shared__ __align__(16) unsigned short As[128 * 32];
    __shared__ __align__(16) unsigned short Bs[128 * 32];
    int tid = threadIdx.x;
    int wv = tid >> 6, lane = tid & 63;
    int wr = wv >> 1, wc = wv & 1;
    int l15 = lane & 15, lg = lane >> 4;
    int tm = blockIdx.y * 128, tn = blockIdx.x * 128;
    f32x4 acc[4][4] = {};

    int lrow = lane >> 2, lcol = (lane & 3) * 8;

    for (int kt = 0; kt < K; kt += 32) {
        __syncthreads();
#pragma unroll
        for (int c = 0; c < 2; ++c) {
            int chunk = wv + c * 4;
            gload_lds16(A + (size_t)(tm + chunk * 16 + lrow) * K + kt + lcol, As + chunk * 512);
            gload_lds16(Bt + (size_t)(tn + chunk * 16 + lrow) * K + kt + lcol, Bs + chunk * 512);
        }
        __syncthreads();
        bf16x8 af[4], bfr[4];
#pragma unroll
        for (int m = 0; m < 4; ++m)
            af[m] = *(const bf16x8*)(As + (wr * 64 + m * 16 + l15) * 32 + lg * 8);
#pragma unroll
        for (int n = 0; n < 4; ++n)
            bfr[n] = *(const bf16x8*)(Bs + (wc * 64 + n * 16 + l15) * 32 + lg * 8);
#pragma unroll
        for (int m = 0; m < 4; ++m)
#pragma unroll
            for (int n = 0; n < 4; ++n)
                acc[m][n] = __builtin_amdgcn_mfma_f32_16x16x32_bf16(af[m], bfr[n], acc[m][n], 0, 0, 0);
    }

    if (EPI == 0) {
#pragma unroll
        for (int m = 0; m < 4; ++m) {
            int row0 = tm + wr * 64 + m * 16 + lg * 4;
#pragma unroll
            for (int n = 0; n < 4; ++n) {
                int col = tn + wc * 64 + n * 16 + l15;
#pragma unroll
                for (int r = 0; r < 4; ++r)
                    C[(size_t)(row0 + r) * N + col] = acc[m][n][r];
            }
        }
    } else {
        const float SC = 0.125f * 1.44269504f;   // folded into Q
#pragma unroll
        for (int m = 0; m < 4; ++m) {
            int row0 = tm + wr * 64 + m * 16 + lg * 4;
#pragma unroll
            for (int n = 0; n < 4; ++n) {
                int e = tn + wc * 64 + n * 16 + l15;
                int sec = e >> 10, rem = e & 1023;
                int h = rem >> 6, hd = rem & 63;
                int tok = row0;
                int b = tok >> 11, tl = tok & 2047;
                if (sec == 2) {
                    size_t idx0 = ((size_t)(b * H_ + h) * HD_ + hd) * T_ + tl;
                    *(unsigned*)(Vo + idx0)     = cvt_pk_bf16(acc[m][n][0], acc[m][n][1]);
                    *(unsigned*)(Vo + idx0 + 2) = cvt_pk_bf16(acc[m][n][2], acc[m][n][3]);
                } else {
                    unsigned short* dst = (sec == 0) ? Qo : Ko;
                    float sc = (sec == 0) ? SC : 1.0f;
#pragma unroll
                    for (int r = 0; r < 4; ++r)
                        dst[(((size_t)(b * H_ + h) * T_ + tl + r) << 6) + hd] =
                            f2bf(acc[m][n][r] * sc);
                }
            }
        }
    }
}

// ---------------- flash attention v11: 32x32 MFMA + full-tile reg prefetch ----------
// v10 structure, two changes: (1) loads for tile t+1 issued right after staging writes
// of tile t (load->use distance = whole tile compute, hides HBM/L2 latency, no extra
// LDS/barriers); (2) no softmax shift at all (2^-M0 cancels in O/l exactly).
#define KPAD 72
#define VPAD 136

#define EXCH(PV, HF, FRAG)                                                     \
  do {                                                                         \
    unsigned uA0 = cvt_pk_bf16(PV[8 * HF + 0], PV[8 * HF + 1]);                \
    unsigned uA1 = cvt_pk_bf16(PV[8 * HF + 2], PV[8 * HF + 3]);                \
    unsigned uB0 = cvt_pk_bf16(PV[8 * HF + 4], PV[8 * HF + 5]);                \
    unsigned uB1 = cvt_pk_bf16(PV[8 * HF + 6], PV[8 * HF + 7]);                \
    unsigned snd0 = hi ? uA0 : uB0, snd1 = hi ? uA1 : uB1;                     \
    unsigned rc0 = (unsigned)__shfl_xor((int)snd0, 32);                        \
    unsigned rc1 = (unsigned)__shfl_xor((int)snd1, 32);                        \
    union { bf16x8 v; unsigned u[4]; } Fx;                                     \
    Fx.u[0] = hi ? rc0 : uA0;                                                  \
    Fx.u[1] = hi ? rc1 : uA1;                                                  \
    Fx.u[2] = hi ? uB0 : rc0;                                                  \
    Fx.u[3] = hi ? uB1 : rc1;                                                  \
    FRAG = Fx.v;                                                               \
  } while (0)

__global__ __launch_bounds__(256) void flash_attn(
    const unsigned short* __restrict__ Qg, const unsigned short* __restrict__ Kg,
    const unsigned short* __restrict__ VTg, const int* __restrict__ mask,
    unsigned short* __restrict__ AO) {
    __shared__ __align__(16) unsigned short Ks[128 * KPAD];
    __shared__ __align__(16) unsigned short VTs[64 * VPAD];
    __shared__ float biasS[128];

    int tid = threadIdx.x, wv = tid >> 6, lane = tid & 63;
    int l31 = lane & 31, hi = lane >> 5;
    int bh = blockIdx.y;
    int b = bh >> 4, h = bh & 15;
    int q0 = blockIdx.x * 128;
    const unsigned short* Qb  = Qg  + (size_t)bh * T_ * HD_;
    const unsigned short* Kb  = Kg  + (size_t)bh * T_ * HD_;
    const unsigned short* VTb = VTg + (size_t)bh * HD_ * T_;

    // Q fragments direct from global: B-frag col=q(l31), kdim=8*hi+jj, hd = c*16+8*hi+jj
    bf16x8 qf[4];
    {
        const unsigned short* qrow = Qb + (size_t)(q0 + wv * 32 + l31) * HD_;
#pragma unroll
        for (int c = 0; c < 4; ++c)
            qf[c] = *(const bf16x8*)(qrow + c * 16 + hi * 8);
    }

    float l_part = 0.f;
    f32x16 o0 = {}, o1 = {};   // O[q-row][d = {0,1}*32 + l31]

    // prologue: tile-0 loads into regs
    i32x4 kv[4], vvv[4];
#pragma unroll
    for (int c = 0; c < 4; ++c) {
        int idx = tid + c * 256;
        kv[c]  = *(const i32x4*)(Kb + (size_t)(idx >> 3) * HD_ + (idx & 7) * 8);
        vvv[c] = *(const i32x4*)(VTb + (size_t)(idx >> 4) * T_ + (idx & 15) * 8);
    }
    int mA = mask[b * T_ + lane];
    int mB = mask[b * T_ + 64 + lane];

    for (int kt = 0; kt < T_; kt += 128) {
        bool nomask = __all(mA != 0 && mB != 0);
        __syncthreads();   // prev tile LDS reads done
#pragma unroll
        for (int c = 0; c < 4; ++c) {
            int idx = tid + c * 256;
            *(i32x4*)(Ks + (idx >> 3) * KPAD + (idx & 7) * 8) = kv[c];
            *(i32x4*)(VTs + (idx >> 4) * VPAD + (idx & 15) * 8) = vvv[c];
        }
        if (!nomask && wv == 0) {
            biasS[lane]      = mA ? 0.f : -1e30f;
            biasS[64 + lane] = mB ? 0.f : -1e30f;
        }
        // issue NEXT tile's loads now: load->use gap spans this tile's compute
        if (kt + 128 < T_) {
#pragma unroll
            for (int c = 0; c < 4; ++c) {
                int idx = tid + c * 256;
                kv[c]  = *(const i32x4*)(Kb + (size_t)(kt + 128 + (idx >> 3)) * HD_ + (idx & 7) * 8);
                vvv[c] = *(const i32x4*)(VTb + (size_t)(idx >> 4) * T_ + kt + 128 + (idx & 15) * 8);
            }
            mA = mask[b * T_ + kt + 128 + lane];
            mB = mask[b * T_ + kt + 192 + lane];
        }
        __syncthreads();   // this tile's LDS ready

        // two 64-key half-passes (keeps S register footprint at 32 f32)
#pragma unroll
        for (int hp = 0; hp < 2; ++hp) {
            f32x16 s0 = {}, s1 = {};
            __builtin_amdgcn_s_setprio(1);
#pragma unroll
            for (int c = 0; c < 4; ++c) {
                bf16x8 ka = *(const bf16x8*)(Ks + ((hp * 2 + 0) * 32 + l31) * KPAD + c * 16 + hi * 8);
                s0 = MFMA32(ka, qf[c], s0);
            }
#pragma unroll
            for (int c = 0; c < 4; ++c) {
                bf16x8 kb2 = *(const bf16x8*)(Ks + ((hp * 2 + 1) * 32 + l31) * KPAD + c * 16 + hi * 8);
                s1 = MFMA32(kb2, qf[c], s1);
            }
            __builtin_amdgcn_s_setprio(0);

            if (!nomask) {
#pragma unroll
                for (int i = 0; i < 16; ++i) {
                    int krow = (i & 3) + 8 * (i >> 2) + 4 * hi;
                    s0[i] += biasS[hp * 64 + krow];
                    s1[i] += biasS[hp * 64 + 32 + krow];
                }
            }
            // P = exp2(S) in place (no shift: constant factor cancels in O/l)
#pragma unroll
            for (int i = 0; i < 16; ++i) {
                s0[i] = exp2a(s0[i]);
                s1[i] = exp2a(s1[i]);
                l_part += s0[i] + s1[i];
            }
            // build 4 PV A-frags (k chunks of 16)
            bf16x8 fr0, fr1, fr2, fr3;
            EXCH(s0, 0, fr0);
            EXCH(s0, 1, fr1);
            EXCH(s1, 0, fr2);
            EXCH(s1, 1, fr3);

            __builtin_amdgcn_s_setprio(1);
#pragma unroll
            for (int kc = 0; kc < 4; ++kc) {
                bf16x8 fr = (kc == 0) ? fr0 : (kc == 1) ? fr1 : (kc == 2) ? fr2 : fr3;
                bf16x8 va = *(const bf16x8*)(VTs + l31 * VPAD + hp * 64 + kc * 16 + hi * 8);
                bf16x8 vb = *(const bf16x8*)(VTs + (32 + l31) * VPAD + hp * 64 + kc * 16 + hi * 8);
                o0 = MFMA32(fr, va, o0);
                o1 = MFMA32(fr, vb, o1);
            }
            __builtin_amdgcn_s_setprio(0);
        }
    }

    // merge l halves (hi=0 owns half the k's, hi=1 the other) -> full l per q=l31
    l_part += __shfl_xor(l_part, 32);

    // write AO[b][t=q0+wv*32+q_row][h*64 + dblk*32 + l31]
    size_t rowD = (size_t)(b * T_ + q0 + wv * 32) * D_ + h * 64;
#pragma unroll
    for (int i = 0; i < 16; ++i) {
        int qrow = (i & 3) + 8 * (i >> 2) + 4 * hi;
        float lq = __shfl(l_part, qrow);
        float inv = 1.0f / lq;
        AO[rowD + (size_t)qrow * D_ + l31]      = f2bf(o0[i] * inv);
        AO[rowD + (size_t)qrow * D_ + 32 + l31] = f2bf(o1[i] * inv);
    }
}

extern "C" void kernel_launch(void* const* d_in, const int* in_sizes, int n_in,
                              void* d_out, int out_size, void* d_ws, size_t ws_size,
                              hipStream_t stream) {
    const float* x    = (const float*)d_in[0];
    const int*   mask = (const int*)d_in[1];
    const float* Wqkv = (const float*)d_in[2];
    const float* Wout = (const float*)d_in[3];
    float* out = (float*)d_out;
    char* ws = (char*)d_ws;

    unsigned short* Xb    = (unsigned short*)(ws);                       // 8 MB
    unsigned short* WqkvT = (unsigned short*)(ws + (size_t)(8u << 20));  // 6 MB
    unsigned short* WoutT = (unsigned short*)(ws + (size_t)(14u << 20)); // 2 MB
    unsigned short* Qg    = (unsigned short*)(ws + (size_t)(16u << 20)); // 8 MB
    unsigned short* Kg    = (unsigned short*)(ws + (size_t)(24u << 20)); // 8 MB
    unsigned short* VT    = (unsigned short*)(ws + (size_t)(32u << 20)); // 8 MB (V transposed)
    unsigned short* AO    = Xb;  // overlay: Xb dead after QKV GEMM

    cast_f32_bf16<<<2048, 256, 0, stream>>>(x, Xb, NT_ * D_);
    transpose_cast<<<dim3(3072 / 32, 1024 / 32), dim3(32, 8), 0, stream>>>(Wqkv, WqkvT, 1024, 3072);
    transpose_cast<<<dim3(1024 / 32, 1024 / 32), dim3(32, 8), 0, stream>>>(Wout, WoutT, 1024, 1024);
    gemm_bt<1><<<dim3(3072 / 128, 4096 / 128), 256, 0, stream>>>(
        Xb, WqkvT, nullptr, Qg, Kg, VT, NT_, 3 * D_, D_);
    flash_attn<<<dim3(T_ / 128, B_ * H_), 256, 0, stream>>>(Qg, Kg, VT, mask, AO);
    gemm_bt<0><<<dim3(1024 / 128, 4096 / 128), 256, 0, stream>>>(
        AO, WoutT, out, nullptr, nullptr, nullptr, NT_, D_, D_);
}